// Round 4
// baseline (63556.622 us; speedup 1.0000x reference)
//
#include <hip/hip_runtime.h>
#include <hip/hip_bf16.h>
#include <hip/hip_cooperative_groups.h>

namespace cg = cooperative_groups;

#define B_   64
#define S_   512
#define I_   512
#define H_   1024
#define G4H  4096
#define O_   512
#define CH_  64   // timesteps per chunk

typedef short s16x8 __attribute__((ext_vector_type(8)));
typedef short s16x4 __attribute__((ext_vector_type(4)));
typedef float f32x4 __attribute__((ext_vector_type(4)));
using bf16 = __hip_bfloat16;

__device__ __forceinline__ float bf2f(bf16 v) { return __bfloat162float(v); }
__device__ __forceinline__ bf16  f2bf(float f) { return __float2bfloat16(f); }
__device__ __forceinline__ short f2bfb(float f) { bf16 h = __float2bfloat16(f); return *(short*)&h; }

__device__ __forceinline__ void storeC(float* p, float v) { *p = v; }
__device__ __forceinline__ void storeC(bf16* p, float v)  { *p = f2bf(v); }

// ---------------------------------------------------------------------------
// C = A @ Bw^T (+bias1+bias2). Bw fp32 global (bf16-converted while staging).
// A is fp32 (ABF=0) or bf16 (ABF=1). fp32 MFMA accum; C bf16 or fp32 (CT).
// AMAP 0: a_row = m                       (chunk layout [t][b] rows)
// AMAP 1: a_row = (m&63)*S + t0 + (m>>6)  (gather from x [B][S][I])
// CMAP 0: c_row = m
// CMAP 2: c_row = (m&63)*S + t0 + (m>>6)  (scatter to out [B*S][O])
// Tile 128x128, BK=32, 256 threads (4 waves, 64x64 quadrant each).
// ---------------------------------------------------------------------------
template <int AMAP, int CMAP, int ABF, typename CT>
__global__ __launch_bounds__(256) void gemm_bt(
    const void* __restrict__ Av, const float* __restrict__ Bw,
    CT* __restrict__ C,
    const float* __restrict__ bias1, const float* __restrict__ bias2,
    int M, int N, int K, int t0)
{
    __shared__ bf16 As[128 * 40];
    __shared__ bf16 Bs[128 * 40];

    const int tid  = threadIdx.x;
    const int wave = tid >> 6;
    const int lane = tid & 63;
    const int quad = lane >> 4;
    const int l16  = lane & 15;

    const int m_base = blockIdx.x * 128;
    const int n_base = blockIdx.y * 128;
    const int wm = (wave >> 1) * 64;
    const int wn = (wave & 1) * 64;

    f32x4 acc[4][4] = {};

    for (int k0 = 0; k0 < K; k0 += 32) {
        __syncthreads();
#pragma unroll
        for (int i = 0; i < 2; i++) {
            int l   = tid + i * 256;     // 0..511
            int row = l >> 2;            // 0..127
            int ko  = (l & 3) * 8;       // 0,8,16,24
            int m   = m_base + row;
            long ar = m;
            if (AMAP == 1) ar = (long)(m & 63) * S_ + t0 + (m >> 6);

            if (ABF) {
                const bf16* ap = (const bf16*)Av + ar * (long)K + k0 + ko;
                *(s16x8*)(&As[row * 40 + ko]) = *(const s16x8*)ap;
            } else {
                const float* ap = (const float*)Av + ar * (long)K + k0 + ko;
                f32x4 a0 = *(const f32x4*)ap;
                f32x4 a1 = *(const f32x4*)(ap + 4);
                s16x8 av;
#pragma unroll
                for (int j = 0; j < 4; j++) { av[j] = f2bfb(a0[j]); av[4 + j] = f2bfb(a1[j]); }
                *(s16x8*)(&As[row * 40 + ko]) = av;
            }

            const float* bp = &Bw[(long)(n_base + row) * K + k0 + ko];
            f32x4 b0 = *(const f32x4*)bp;
            f32x4 b1 = *(const f32x4*)(bp + 4);
            s16x8 bv;
#pragma unroll
            for (int j = 0; j < 4; j++) { bv[j] = f2bfb(b0[j]); bv[4 + j] = f2bfb(b1[j]); }
            *(s16x8*)(&Bs[row * 40 + ko]) = bv;
        }
        __syncthreads();

        s16x8 af[4], bfr[4];
#pragma unroll
        for (int i = 0; i < 4; i++)
            af[i] = *(const s16x8*)(&As[(wm + i * 16 + l16) * 40 + quad * 8]);
#pragma unroll
        for (int j = 0; j < 4; j++)
            bfr[j] = *(const s16x8*)(&Bs[(wn + j * 16 + l16) * 40 + quad * 8]);
#pragma unroll
        for (int i = 0; i < 4; i++)
#pragma unroll
            for (int j = 0; j < 4; j++)
                acc[i][j] = __builtin_amdgcn_mfma_f32_16x16x32_bf16(af[i], bfr[j], acc[i][j], 0, 0, 0);
    }

    // C/D layout: col = lane&15, row = (lane>>4)*4 + reg
#pragma unroll
    for (int i = 0; i < 4; i++) {
#pragma unroll
        for (int j = 0; j < 4; j++) {
#pragma unroll
            for (int r = 0; r < 4; r++) {
                int m = m_base + wm + i * 16 + quad * 4 + r;
                int n = n_base + wn + j * 16 + l16;
                float v = acc[i][j][r];
                if (bias1) v += bias1[n];
                if (bias2) v += bias2[n];
                long cr = m;
                if (CMAP == 2) cr = (long)(m & 63) * S_ + t0 + (m >> 6);
                storeC(&C[cr * (long)N + n], v);
            }
        }
    }
}

// ---------------------------------------------------------------------------
// Persistent chunk recurrence: nsteps LSTM timesteps in ONE cooperative launch.
// Grid: 256 blocks x 256 threads (1 block/CU). Block nb owns gate-cols
// {g*H + nb*4 + u : g in 0..3, u in 0..3}. Whh slice (16 rows x 1024) cached
// in LDS (fp32->bf16 at entry). c-state lives in a register per thread.
// Per step: grid-wide barrier via cg::this_grid().sync().
// ---------------------------------------------------------------------------
__global__ __launch_bounds__(256) void lstm_seq(
    const bf16* __restrict__ xg,   // [CH][B][4H]
    const float* __restrict__ Whh, // [4H][H] fp32
    bf16* __restrict__ hbuf,       // [CH+1][B][H]
    float* __restrict__ c,         // [B][H] fp32
    int nsteps)
{
    const int tid  = threadIdx.x;
    const int lane = tid & 63;
    const int wave = tid >> 6;
    const int quad = lane >> 4;
    const int l16  = lane & 15;
    const int nb   = blockIdx.x;

    __shared__ bf16 wsh[16][1032];   // +8 pad: 2-way bank aliasing only (free)
    __shared__ float gs[64][17];

    // stage Whh slice into LDS (16 rows x 1024), fp32 -> bf16
    {
        int r  = tid >> 4;                 // 0..15
        int c0 = (tid & 15) * 64;          // 64 elems per thread
        long jrow = (long)(r >> 2) * H_ + nb * 4 + (r & 3);
        const float* src = Whh + jrow * H_ + c0;
#pragma unroll
        for (int j = 0; j < 64; j += 4) {
            f32x4 v = *(const f32x4*)(src + j);
            s16x4 o;
#pragma unroll
            for (int q = 0; q < 4; q++) o[q] = f2bfb(v[q]);
            *(s16x4*)(&wsh[r][c0 + j]) = o;
        }
    }
    __syncthreads();

    const int jcol = (l16 >> 2) * H_ + nb * 4 + (l16 & 3);
    const int u    = tid & 3;
    const int bb   = tid >> 2;
    const int unit = nb * 4 + u;

    float ccur = c[bb * H_ + unit];

    cg::grid_group grid = cg::this_grid();

    for (int t = 0; t < nsteps; t++) {
        const bf16* aptr = hbuf + (long)t * (B_ * H_) + (long)(wave * 16 + l16) * H_ + quad * 8;
        f32x4 acc = {};
#pragma unroll 8
        for (int k = 0; k < H_; k += 32) {
            s16x8 a = *(const s16x8*)(aptr + k);
            s16x8 b = *(const s16x8*)(&wsh[l16][k + quad * 8]);
            acc = __builtin_amdgcn_mfma_f32_16x16x32_bf16(a, b, acc, 0, 0, 0);
        }

        const bf16* xgt = xg + (long)t * (B_ * G4H);
#pragma unroll
        for (int r = 0; r < 4; r++) {
            int brow = wave * 16 + quad * 4 + r;
            gs[brow][l16] = acc[r] + bf2f(xgt[(long)brow * G4H + jcol]);
        }
        __syncthreads();

        float gi = gs[bb][0 + u];
        float gf = gs[bb][4 + u];
        float gg = gs[bb][8 + u];
        float go = gs[bb][12 + u];

        float ig = 1.f / (1.f + __expf(-gi));
        float fg = 1.f / (1.f + __expf(-gf));
        float og = 1.f / (1.f + __expf(-go));
        float e2 = __expf(-2.f * fabsf(gg));
        float tg = (1.f - e2) / (1.f + e2);
        tg = (gg < 0.f) ? -tg : tg;

        ccur = fg * ccur + ig * tg;
        float e2c = __expf(-2.f * fabsf(ccur));
        float tc = (1.f - e2c) / (1.f + e2c);
        tc = (ccur < 0.f) ? -tc : tc;

        bf16 hv = f2bf(og * tc);
        hbuf[(long)(t + 1) * (B_ * H_) + (long)bb * H_ + unit] = hv;
        if (t == nsteps - 1)
            hbuf[(long)bb * H_ + unit] = hv;   // carry to slot 0 for next chunk

        __threadfence();
        grid.sync();
    }

    c[bb * H_ + unit] = ccur;
}

__global__ __launch_bounds__(256) void init_k(float* c0, float* c1, bf16* h0, bf16* h1)
{
    int i = blockIdx.x * 256 + threadIdx.x;
    if (i < B_ * H_) {
        c0[i] = 0.f; c1[i] = 0.f;
        h0[i] = f2bf(0.f); h1[i] = f2bf(0.f);
    }
}

__global__ __launch_bounds__(256) void finalize_k(
    const bf16* __restrict__ h0, const bf16* __restrict__ h1,
    const float* __restrict__ c0, const float* __restrict__ c1,
    float* __restrict__ out_hn, float* __restrict__ out_cn)
{
    int i = blockIdx.x * 256 + threadIdx.x;
    if (i < B_ * H_) {
        out_hn[i]            = bf2f(h0[i]);   // slot 0 holds final h after last chunk
        out_hn[B_ * H_ + i]  = bf2f(h1[i]);
        out_cn[i]            = c0[i];
        out_cn[B_ * H_ + i]  = c1[i];
    }
}

extern "C" void kernel_launch(void* const* d_in, const int* in_sizes, int n_in,
                              void* d_out, int out_size, void* d_ws, size_t ws_size,
                              hipStream_t stream)
{
    const float* x    = (const float*)d_in[0];
    const float* Wih0 = (const float*)d_in[1];
    const float* Whh0 = (const float*)d_in[2];
    const float* bih0 = (const float*)d_in[3];
    const float* bhh0 = (const float*)d_in[4];
    const float* Wih1 = (const float*)d_in[5];
    const float* Whh1 = (const float*)d_in[6];
    const float* bih1 = (const float*)d_in[7];
    const float* bhh1 = (const float*)d_in[8];
    const float* Wfc  = (const float*)d_in[9];
    const float* bfc  = (const float*)d_in[10];
    float* out = (float*)d_out;

    // workspace (~51 MB, proven size)
    char* p = (char*)d_ws;
    float* c0 = (float*)p; p += (size_t)B_ * H_ * 4;                  // 256 KB
    float* c1 = (float*)p; p += (size_t)B_ * H_ * 4;                  // 256 KB
    bf16* h0  = (bf16*)p;  p += (size_t)(CH_ + 1) * B_ * H_ * 2;      // 8.5 MB
    bf16* h1  = (bf16*)p;  p += (size_t)(CH_ + 1) * B_ * H_ * 2;      // 8.5 MB
    bf16* xg  = (bf16*)p;  p += (size_t)CH_ * B_ * G4H * 2;           // 33.5 MB

    init_k<<<(B_ * H_ + 255) / 256, 256, 0, stream>>>(c0, c1, h0, h1);

    const dim3 gxg((B_ * CH_) / 128, G4H / 128);   // 32 x 32
    const dim3 gfc((B_ * CH_) / 128, O_ / 128);    // 32 x 4
    int nsteps = CH_;

    for (int cidx = 0; cidx < S_ / CH_; cidx++) {
        const int t0 = cidx * CH_;

        // layer-0 xg: xg[t][b] = x[b][t0+t] @ Wih0^T + bih0 + bhh0   (A fp32)
        gemm_bt<1, 0, 0, bf16><<<gxg, 256, 0, stream>>>(x, Wih0, xg, bih0, bhh0,
                                                        B_ * CH_, G4H, I_, t0);
        {
            const bf16* xgp = xg; const float* wp = Whh0; bf16* hp = h0; float* cp = c0;
            void* args[] = {(void*)&xgp, (void*)&wp, (void*)&hp, (void*)&cp, (void*)&nsteps};
            hipLaunchCooperativeKernel((void*)lstm_seq, dim3(256), dim3(256), args, 0, stream);
        }

        // layer-1 xg: xg[t][b] = h0[t+1][b] @ Wih1^T + bih1 + bhh1   (A bf16)
        gemm_bt<0, 0, 1, bf16><<<gxg, 256, 0, stream>>>(h0 + B_ * H_, Wih1, xg,
                                                        bih1, bhh1,
                                                        B_ * CH_, G4H, H_, 0);
        {
            const bf16* xgp = xg; const float* wp = Whh1; bf16* hp = h1; float* cp = c1;
            void* args[] = {(void*)&xgp, (void*)&wp, (void*)&hp, (void*)&cp, (void*)&nsteps};
            hipLaunchCooperativeKernel((void*)lstm_seq, dim3(256), dim3(256), args, 0, stream);
        }

        // FC: out[b*S + t0 + t] = h1[t+1][b] @ Wfc^T + bfc           (A bf16, C fp32)
        gemm_bt<0, 2, 1, float><<<gfc, 256, 0, stream>>>(h1 + B_ * H_, Wfc, out,
                                                         bfc, (const float*)nullptr,
                                                         B_ * CH_, O_, H_, t0);
    }

    finalize_k<<<(B_ * H_ + 255) / 256, 256, 0, stream>>>(
        h0, h1, c0, c1,
        out + (size_t)B_ * S_ * O_,
        out + (size_t)B_ * S_ * O_ + 2 * (size_t)B_ * H_);
}

// Round 5
// 10497.376 us; speedup vs baseline: 6.0545x; 6.0545x over previous
//
#include <hip/hip_runtime.h>
#include <hip/hip_bf16.h>

#define B_   64
#define S_   512
#define I_   512
#define H_   1024
#define G4H  4096
#define O_   512
#define CH_  32    // timesteps per chunk
#define NCH  (S_ / CH_)   // 16 chunks per layer

typedef short s16x8 __attribute__((ext_vector_type(8)));
typedef short s16x4 __attribute__((ext_vector_type(4)));
typedef float f32x4 __attribute__((ext_vector_type(4)));
using bf16 = __hip_bfloat16;

__device__ __forceinline__ float bf2f(bf16 v) { return __bfloat162float(v); }
__device__ __forceinline__ bf16  f2bf(float f) { return __float2bfloat16(f); }
__device__ __forceinline__ short f2bfb(float f) { bf16 h = __float2bfloat16(f); return *(short*)&h; }

__device__ __forceinline__ void storeC(float* p, float v) { *p = v; }
__device__ __forceinline__ void storeC(bf16* p, float v)  { *p = f2bf(v); }

// ---------------------------------------------------------------------------
// C = A @ Bw^T (+bias1+bias2). Bw fp32 global (bf16-converted while staging).
// A is fp32 (ABF=0) or bf16 (ABF=1). fp32 MFMA accum; C bf16 or fp32 (CT).
// AMAP 0: a_row = m                            (chunk layout [t][b] rows)
// AMAP 1: a_row = (m&63)*S + t0 + (m>>6)       (gather from x [B][S][I])
// CMAP 0: c_row = m
// CMAP 2: c_row = (m&63)*S + t0 + (m>>6)       (scatter to out [B*S][O])
// Tile 128x128, BK=32, 256 threads (4 waves, 64x64 quadrant each).
// ---------------------------------------------------------------------------
template <int AMAP, int CMAP, int ABF, typename CT>
__global__ __launch_bounds__(256) void gemm_bt(
    const void* __restrict__ Av, const float* __restrict__ Bw,
    CT* __restrict__ C,
    const float* __restrict__ bias1, const float* __restrict__ bias2,
    int M, int N, int K, int t0)
{
    __shared__ bf16 As[128 * 40];
    __shared__ bf16 Bs[128 * 40];

    const int tid  = threadIdx.x;
    const int wave = tid >> 6;
    const int lane = tid & 63;
    const int quad = lane >> 4;
    const int l16  = lane & 15;

    const int m_base = blockIdx.x * 128;
    const int n_base = blockIdx.y * 128;
    const int wm = (wave >> 1) * 64;
    const int wn = (wave & 1) * 64;

    f32x4 acc[4][4] = {};

    for (int k0 = 0; k0 < K; k0 += 32) {
        __syncthreads();
#pragma unroll
        for (int i = 0; i < 2; i++) {
            int l   = tid + i * 256;     // 0..511
            int row = l >> 2;            // 0..127
            int ko  = (l & 3) * 8;       // 0,8,16,24
            int m   = m_base + row;
            long ar = m;
            if (AMAP == 1) ar = (long)(m & 63) * S_ + t0 + (m >> 6);

            if (ABF) {
                const bf16* ap = (const bf16*)Av + ar * (long)K + k0 + ko;
                *(s16x8*)(&As[row * 40 + ko]) = *(const s16x8*)ap;
            } else {
                const float* ap = (const float*)Av + ar * (long)K + k0 + ko;
                f32x4 a0 = *(const f32x4*)ap;
                f32x4 a1 = *(const f32x4*)(ap + 4);
                s16x8 av;
#pragma unroll
                for (int j = 0; j < 4; j++) { av[j] = f2bfb(a0[j]); av[4 + j] = f2bfb(a1[j]); }
                *(s16x8*)(&As[row * 40 + ko]) = av;
            }

            const float* bp = &Bw[(long)(n_base + row) * K + k0 + ko];
            f32x4 b0 = *(const f32x4*)bp;
            f32x4 b1 = *(const f32x4*)(bp + 4);
            s16x8 bv;
#pragma unroll
            for (int j = 0; j < 4; j++) { bv[j] = f2bfb(b0[j]); bv[4 + j] = f2bfb(b1[j]); }
            *(s16x8*)(&Bs[row * 40 + ko]) = bv;
        }
        __syncthreads();

        s16x8 af[4], bfr[4];
#pragma unroll
        for (int i = 0; i < 4; i++)
            af[i] = *(const s16x8*)(&As[(wm + i * 16 + l16) * 40 + quad * 8]);
#pragma unroll
        for (int j = 0; j < 4; j++)
            bfr[j] = *(const s16x8*)(&Bs[(wn + j * 16 + l16) * 40 + quad * 8]);
#pragma unroll
        for (int i = 0; i < 4; i++)
#pragma unroll
            for (int j = 0; j < 4; j++)
                acc[i][j] = __builtin_amdgcn_mfma_f32_16x16x32_bf16(af[i], bfr[j], acc[i][j], 0, 0, 0);
    }

    // C/D layout: col = lane&15, row = (lane>>4)*4 + reg
#pragma unroll
    for (int i = 0; i < 4; i++) {
#pragma unroll
        for (int j = 0; j < 4; j++) {
#pragma unroll
            for (int r = 0; r < 4; r++) {
                int m = m_base + wm + i * 16 + quad * 4 + r;
                int n = n_base + wn + j * 16 + l16;
                float v = acc[i][j][r];
                if (bias1) v += bias1[n];
                if (bias2) v += bias2[n];
                long cr = m;
                if (CMAP == 2) cr = (long)(m & 63) * S_ + t0 + (m >> 6);
                storeC(&C[cr * (long)N + n], v);
            }
        }
    }
}

// ---------------------------------------------------------------------------
// One pipelined round: layer-0 does local step j of chunk cpar, layer-1 does
// local step j of chunk cpar-1. Grid 512 blocks x 256 threads:
//   blocks [0,256)   -> layer 0 (active iff do0)
//   blocks [256,512) -> layer 1 (active iff do1)
// Each block owns 4 hidden units (16 gate-cols). Whh slice (16 x 1024) staged
// fp32->bf16 into LDS per round. Kernel boundary = inter-step barrier.
// h0w: [2][CH+1][B][H] (double-buffered window, buf cpar&1 for chunk cpar)
// h1w: [CH+1][B][H]    (single window, carry in slot 0)
// ---------------------------------------------------------------------------
__global__ __launch_bounds__(256) void round_k(
    const bf16* __restrict__ xg0,  // [CH][B][4H] (layer-0 input contrib, chunk cpar)
    const bf16* __restrict__ xg1,  // [CH][B][4H] (layer-1 input contrib, chunk cpar-1)
    const float* __restrict__ Whh0,
    const float* __restrict__ Whh1,
    bf16* __restrict__ h0w,
    bf16* __restrict__ h1w,
    float* __restrict__ c0,
    float* __restrict__ c1,
    int j, int cpar, int do0, int do1)
{
    const int layer = blockIdx.x >> 8;
    if (layer == 0 && !do0) return;
    if (layer == 1 && !do1) return;
    const int nb = blockIdx.x & 255;

    const bf16*  xg  = layer ? xg1  : xg0;
    const float* Whh = layer ? Whh1 : Whh0;
    float*       cst = layer ? c1   : c0;

    bf16* rbuf;    // window base: read slot j, write slot j+1
    bf16* cbuf;    // carry target (slot 0 of next window)
    if (layer == 0) {
        rbuf = h0w + (size_t)(cpar & 1) * (CH_ + 1) * B_ * H_;
        cbuf = h0w + (size_t)((cpar + 1) & 1) * (CH_ + 1) * B_ * H_;
    } else {
        rbuf = h1w;
        cbuf = h1w;
    }

    const int tid  = threadIdx.x;
    const int lane = tid & 63;
    const int wave = tid >> 6;
    const int quad = lane >> 4;
    const int l16  = lane & 15;

    __shared__ bf16 wsh[16][1032];   // +8 pad: 2-way bank aliasing only (free)
    __shared__ float gs[64][17];

    // stage Whh slice (16 gate-rows x 1024) into LDS, fp32 -> bf16
    {
        int r  = tid >> 4;                 // 0..15
        int cc = (tid & 15) * 64;          // 64 elems per thread
        long jrow = (long)(r >> 2) * H_ + nb * 4 + (r & 3);
        const float* src = Whh + jrow * H_ + cc;
#pragma unroll
        for (int q = 0; q < 64; q += 4) {
            f32x4 v = *(const f32x4*)(src + q);
            s16x4 o;
#pragma unroll
            for (int w = 0; w < 4; w++) o[w] = f2bfb(v[w]);
            *(s16x4*)(&wsh[r][cc + q]) = o;
        }
    }
    __syncthreads();

    const int jcol = (l16 >> 2) * H_ + nb * 4 + (l16 & 3);

    const bf16* aptr = rbuf + (long)j * (B_ * H_) + (long)(wave * 16 + l16) * H_ + quad * 8;
    f32x4 acc = {};
#pragma unroll 8
    for (int k = 0; k < H_; k += 32) {
        s16x8 a = *(const s16x8*)(aptr + k);
        s16x8 b = *(const s16x8*)(&wsh[l16][k + quad * 8]);
        acc = __builtin_amdgcn_mfma_f32_16x16x32_bf16(a, b, acc, 0, 0, 0);
    }

    const bf16* xgt = xg + (long)j * (B_ * G4H);
#pragma unroll
    for (int r = 0; r < 4; r++) {
        int brow = wave * 16 + quad * 4 + r;
        gs[brow][l16] = acc[r] + bf2f(xgt[(long)brow * G4H + jcol]);
    }
    __syncthreads();

    const int u  = tid & 3;
    const int bb = tid >> 2;
    float gi = gs[bb][0 + u];
    float gf = gs[bb][4 + u];
    float gg = gs[bb][8 + u];
    float go = gs[bb][12 + u];

    float ig = 1.f / (1.f + __expf(-gi));
    float fg = 1.f / (1.f + __expf(-gf));
    float og = 1.f / (1.f + __expf(-go));
    float e2 = __expf(-2.f * fabsf(gg));
    float tg = (1.f - e2) / (1.f + e2);
    tg = (gg < 0.f) ? -tg : tg;

    const int unit = nb * 4 + u;
    float cold = cst[bb * H_ + unit];
    float cnew = fg * cold + ig * tg;
    cst[bb * H_ + unit] = cnew;
    float e2c = __expf(-2.f * fabsf(cnew));
    float tc = (1.f - e2c) / (1.f + e2c);
    tc = (cnew < 0.f) ? -tc : tc;

    bf16 hv = f2bf(og * tc);
    rbuf[(long)(j + 1) * (B_ * H_) + (long)bb * H_ + unit] = hv;
    if (j == CH_ - 1)
        cbuf[(long)bb * H_ + unit] = hv;   // carry to next window's slot 0
}

// zero c-states and the two carry-in h slots
__global__ __launch_bounds__(256) void init_k(float* c0, float* c1, bf16* h0w, bf16* h1w)
{
    int i = blockIdx.x * 256 + threadIdx.x;
    if (i < B_ * H_) {
        c0[i] = 0.f; c1[i] = 0.f;
        h0w[i] = f2bf(0.f);   // buf 0, slot 0
        h1w[i] = f2bf(0.f);   // slot 0
    }
}

// h_n: layer0 = h0w buf0 slot0 (final carry), layer1 = h1w slot0. c_n fp32.
__global__ __launch_bounds__(256) void finalize_k(
    const bf16* __restrict__ h0w, const bf16* __restrict__ h1w,
    const float* __restrict__ c0, const float* __restrict__ c1,
    float* __restrict__ out_hn, float* __restrict__ out_cn)
{
    int i = blockIdx.x * 256 + threadIdx.x;
    if (i < B_ * H_) {
        out_hn[i]            = bf2f(h0w[i]);
        out_hn[B_ * H_ + i]  = bf2f(h1w[i]);
        out_cn[i]            = c0[i];
        out_cn[B_ * H_ + i]  = c1[i];
    }
}

extern "C" void kernel_launch(void* const* d_in, const int* in_sizes, int n_in,
                              void* d_out, int out_size, void* d_ws, size_t ws_size,
                              hipStream_t stream)
{
    const float* x    = (const float*)d_in[0];
    const float* Wih0 = (const float*)d_in[1];
    const float* Whh0 = (const float*)d_in[2];
    const float* bih0 = (const float*)d_in[3];
    const float* bhh0 = (const float*)d_in[4];
    const float* Wih1 = (const float*)d_in[5];
    const float* Whh1 = (const float*)d_in[6];
    const float* bih1 = (const float*)d_in[7];
    const float* bhh1 = (const float*)d_in[8];
    const float* Wfc  = (const float*)d_in[9];
    const float* bfc  = (const float*)d_in[10];
    float* out = (float*)d_out;

    // workspace (~45 MB)
    char* p = (char*)d_ws;
    float* c0  = (float*)p; p += (size_t)B_ * H_ * 4;                       // 256 KB
    float* c1  = (float*)p; p += (size_t)B_ * H_ * 4;                       // 256 KB
    bf16* h0w  = (bf16*)p;  p += (size_t)2 * (CH_ + 1) * B_ * H_ * 2;       // 8.25 MB
    bf16* h1w  = (bf16*)p;  p += (size_t)(CH_ + 1) * B_ * H_ * 2;           // 4.13 MB
    bf16* xg0  = (bf16*)p;  p += (size_t)CH_ * B_ * G4H * 2;                // 16 MB
    bf16* xg1  = (bf16*)p;  p += (size_t)CH_ * B_ * G4H * 2;                // 16 MB

    init_k<<<(B_ * H_ + 255) / 256, 256, 0, stream>>>(c0, c1, h0w, h1w);

    const dim3 gxg0((B_ * CH_) / 128, G4H / 128);  // 16 x 32
    const dim3 gfc((B_ * CH_) / 128, O_ / 128);    // 16 x 4

    // Diagonal pipeline over 17 groups: layer0 on chunk c, layer1 on chunk c-1.
    for (int c = 0; c <= NCH; c++) {
        const int do0 = (c < NCH);
        const int do1 = (c >= 1);

        if (do0) {
            // xg0(c): xg0[t][b] = x[b][c*CH+t] @ Wih0^T + bih0 + bhh0   (A fp32)
            gemm_bt<1, 0, 0, bf16><<<gxg0, 256, 0, stream>>>(
                x, Wih0, xg0, bih0, bhh0, B_ * CH_, G4H, I_, c * CH_);
        }
        if (do1) {
            // xg1(c-1): from h0 window buf (c-1)&1, slots 1..CH           (A bf16)
            const bf16* h0chunk = h0w + (size_t)((c - 1) & 1) * (CH_ + 1) * B_ * H_ + B_ * H_;
            gemm_bt<0, 0, 1, bf16><<<gxg0, 256, 0, stream>>>(
                h0chunk, Wih1, xg1, bih1, bhh1, B_ * CH_, G4H, H_, 0);
        }

        for (int j = 0; j < CH_; j++)
            round_k<<<512, 256, 0, stream>>>(xg0, xg1, Whh0, Whh1,
                                             h0w, h1w, c0, c1, j, c, do0, do1);

        if (do1) {
            // FC on layer-1 chunk c-1: out rows t0=(c-1)*CH              (A bf16, C fp32)
            gemm_bt<0, 2, 1, float><<<gfc, 256, 0, stream>>>(
                h1w + B_ * H_, Wfc, out, bfc, (const float*)nullptr,
                B_ * CH_, O_, H_, (c - 1) * CH_);
        }
    }

    finalize_k<<<(B_ * H_ + 255) / 256, 256, 0, stream>>>(
        h0w, h1w, c0, c1,
        out + (size_t)B_ * S_ * O_,
        out + (size_t)B_ * S_ * O_ + 2 * (size_t)B_ * H_);
}